// Round 9
// baseline (54.328 us; speedup 1.0000x reference)
//
#include <hip/hip_runtime.h>

#define DD 6
#define FF 64
#define LN_EPS 1e-5f

typedef float f32x2 __attribute__((ext_vector_type(2)));
typedef float f32x4 __attribute__((ext_vector_type(4)));

// DPP cross-lane move within a 16-lane row (VALU pipe, not DS).
// 0x140=row_mirror (l^15), 0x141=row_half_mirror (l^7),
// 0x4E=quad_perm[2,3,0,1] (l^2), 0xB1=quad_perm[1,0,3,2] (l^1).
template <int CTRL>
__device__ inline float dpp_mov(float x) {
    return __int_as_float(__builtin_amdgcn_update_dpp(
        0, __float_as_int(x), CTRL, 0xF, 0xF, true));
}

// Pass 1: fused stalk-mean + per-entity LN/matvec partials.
// tab[ent*8] = {S, SS, d0..d5} with S=sum_k m_k, SS=sum_k m_k^2,
// d_j = sum_k m_k*gamma[base+k]*W[base+k][j] (base 0 nodes / 64 edges).
// 16-lane group handles entity pair (A=2p, B=2p+1); lane gl owns feats
// 4gl..4gl+3. DPP butterfly leaves lane gl holding value index gl
// (0..7 = A, 8..15 = B) -> contiguous 64B store per group.
// One-shot (one pair per group): straight-line body lets the allocator
// batch all 12 dwordx4 loads. Persistent grid-stride variants (R6/R7)
// compiled to VGPR=48 serialized loads, 3x slower — do not re-fuse.
// Block 0 threads 0..11 also compute gw_j / bw_j scalars.
__global__ __launch_bounds__(256) void entity_kernel(
    const float* __restrict__ x, const float* __restrict__ e,
    const float* __restrict__ gamma, const float* __restrict__ beta,
    const float* __restrict__ W, const float* __restrict__ b,
    float* __restrict__ nodeT, float* __restrict__ edgeT,
    float* __restrict__ gwbw, int N, int E) {
    if (blockIdx.x == 0 && threadIdx.x < 12) {
        const int t = threadIdx.x;
        const int j = (t < 6) ? t : t - 6;
        const float* g = (t < 6) ? gamma : beta;
        float s = (t < 6) ? 0.f : b[j];
        for (int k = 0; k < 2 * FF; ++k) s = fmaf(g[k], W[k * DD + j], s);
        gwbw[t] = s;
    }

    const int gl = threadIdx.x & 15;
    const int nodePairs = (N + 1) >> 1;
    const int edgePairs = (E + 1) >> 1;
    const int p = blockIdx.x * 16 + (threadIdx.x >> 4);
    if (p >= nodePairs + edgePairs) return;

    const float* in; float* tab; int A, last, kbase;
    if (p < nodePairs) {
        in = x; tab = nodeT; A = 2 * p; last = N - 1; kbase = 0;
    } else {
        in = e; tab = edgeT; A = 2 * (p - nodePairs); last = E - 1; kbase = FF;
    }
    const int B = A + 1;
    const bool bval = (B <= last);
    const int Bc = bval ? B : A;

    // Issue the 12 float4 data loads first to overlap the gamma*W hoist.
    const float4* pa = reinterpret_cast<const float4*>(in + (size_t)A * (DD * FF)) + gl;
    const float4* pb = reinterpret_cast<const float4*>(in + (size_t)Bc * (DD * FF)) + gl;
    float4 va[DD], vb[DD];
#pragma unroll
    for (int d = 0; d < DD; ++d) { va[d] = pa[d * 16]; vb[d] = pb[d * 16]; }

    float gwl[4][6];
#pragma unroll
    for (int c = 0; c < 4; ++c) {
        const int k = kbase + 4 * gl + c;
        const float gk = gamma[k];
#pragma unroll
        for (int j = 0; j < 6; ++j) gwl[c][j] = gk * W[k * DD + j];
    }

    float mA[4], mB[4];
    {
        float s0 = 0.f, s1 = 0.f, s2 = 0.f, s3 = 0.f;
        float u0 = 0.f, u1 = 0.f, u2 = 0.f, u3 = 0.f;
#pragma unroll
        for (int d = 0; d < DD; ++d) {
            s0 += va[d].x; s1 += va[d].y; s2 += va[d].z; s3 += va[d].w;
            u0 += vb[d].x; u1 += vb[d].y; u2 += vb[d].z; u3 += vb[d].w;
        }
        const float inv6 = 1.0f / 6.0f;
        mA[0] = s0 * inv6; mA[1] = s1 * inv6; mA[2] = s2 * inv6; mA[3] = s3 * inv6;
        mB[0] = u0 * inv6; mB[1] = u1 * inv6; mB[2] = u2 * inv6; mB[3] = u3 * inv6;
    }

    // v[0]=SA v[1]=SSA v[2..7]=dA[0..5] v[8]=SB v[9]=SSB v[10..15]=dB
    float v[16];
#pragma unroll
    for (int k = 0; k < 16; ++k) v[k] = 0.f;
#pragma unroll
    for (int c = 0; c < 4; ++c) {
        v[0] += mA[c];
        v[1] = fmaf(mA[c], mA[c], v[1]);
        v[8] += mB[c];
        v[9] = fmaf(mB[c], mB[c], v[9]);
#pragma unroll
        for (int j = 0; j < 6; ++j) {
            v[2 + j]  = fmaf(mA[c], gwl[c][j], v[2 + j]);
            v[10 + j] = fmaf(mB[c], gwl[c][j], v[10 + j]);
        }
    }

    float t[16];
    // stage 1: partner l^15 (row_mirror), predicate bit3; live 16 -> 8
#pragma unroll
    for (int k = 0; k < 16; ++k) t[k] = dpp_mov<0x140>(v[k]);
    if (gl & 8) {
#pragma unroll
        for (int k = 0; k < 8; ++k) { v[k] = v[8 + k]; t[k] = t[8 + k]; }
    }
#pragma unroll
    for (int k = 0; k < 8; ++k) v[k] += t[k];
    // stage 2: partner l^7 (row_half_mirror), predicate bit2; live 8 -> 4
#pragma unroll
    for (int k = 0; k < 8; ++k) t[k] = dpp_mov<0x141>(v[k]);
    if (gl & 4) {
#pragma unroll
        for (int k = 0; k < 4; ++k) { v[k] = v[4 + k]; t[k] = t[4 + k]; }
    }
#pragma unroll
    for (int k = 0; k < 4; ++k) v[k] += t[k];
    // stage 3: partner l^2 (quad_perm[2,3,0,1]), predicate bit1; live 4 -> 2
#pragma unroll
    for (int k = 0; k < 4; ++k) t[k] = dpp_mov<0x4E>(v[k]);
    if (gl & 2) { v[0] = v[2]; t[0] = t[2]; v[1] = v[3]; t[1] = t[3]; }
    v[0] += t[0]; v[1] += t[1];
    // stage 4: partner l^1 (quad_perm[1,0,3,2]), predicate bit0; live 2 -> 1
    t[0] = dpp_mov<0xB1>(v[0]);
    t[1] = dpp_mov<0xB1>(v[1]);
    if (gl & 1) { v[0] = v[1]; t[0] = t[1]; }
    const float r = v[0] + t[0];   // lane gl holds total of value index gl

    if (gl < 8) {
        tab[(size_t)A * 8 + gl] = r;
    } else if (bval) {
        tab[(size_t)B * 8 + (gl & 7)] = r;
    }
}

// Pass 2: TWO incidences per thread, no LDS. Indices via coalesced int2;
// 8 independent 16B gathers (tables L2/L3-resident); 12 contiguous output
// floats -> exactly 3 dwordx4 NT stores (the 3 instructions jointly cover
// the wave's 3KB span with full lines). No transpose, no barrier.
__global__ __launch_bounds__(256) void incidence2_kernel(
    const float* __restrict__ nodeT, const float* __restrict__ edgeT,
    const int* __restrict__ row, const int* __restrict__ col,
    const float* __restrict__ gwbw, float* __restrict__ out, int nnz) {
    const int t = blockIdx.x * blockDim.x + threadIdx.x;
    const int i0 = 2 * t;
    if (i0 >= nnz) return;
    const bool two = (i0 + 1 < nnz);

    int r0, r1, c0, c1;
    if (two) {
        const int2 rv = *reinterpret_cast<const int2*>(row + i0);
        const int2 cv = *reinterpret_cast<const int2*>(col + i0);
        r0 = rv.x; r1 = rv.y; c0 = cv.x; c1 = cv.y;
    } else {
        r0 = row[i0]; c0 = col[i0]; r1 = r0; c1 = c0;
    }

    // 8 independent gathers, issued as one batch.
    const float4* n0 = reinterpret_cast<const float4*>(nodeT + (size_t)r0 * 8);
    const float4* n1 = reinterpret_cast<const float4*>(nodeT + (size_t)r1 * 8);
    const float4* e0 = reinterpret_cast<const float4*>(edgeT + (size_t)c0 * 8);
    const float4* e1 = reinterpret_cast<const float4*>(edgeT + (size_t)c1 * 8);
    const float4 na = n0[0], nb = n0[1];
    const float4 ma = n1[0], mb = n1[1];
    const float4 ea = e0[0], eb = e0[1];
    const float4 fa = e1[0], fb = e1[1];

    float gwv[12];
#pragma unroll
    for (int j = 0; j < 12; ++j) gwv[j] = gwbw[j];   // uniform -> s_load

    float p0[6], p1[6];
    {
        const float S  = na.x + ea.x;
        const float SS = na.y + ea.y;
        const float d[6] = {na.z + ea.z, na.w + ea.w, nb.x + eb.x,
                            nb.y + eb.y, nb.z + eb.z, nb.w + eb.w};
        const float mu  = S * (1.0f / 128.0f);
        const float var = fmaf(SS, 1.0f / 128.0f, -mu * mu);
        const float inv = rsqrtf(var + LN_EPS);
#pragma unroll
        for (int j = 0; j < 6; ++j) {
            const float pre = fmaf(inv, fmaf(-mu, gwv[j], d[j]), gwv[6 + j]);
            p0[j] = 1.0f / (1.0f + __expf(-pre));
        }
    }
    {
        const float S  = ma.x + fa.x;
        const float SS = ma.y + fa.y;
        const float d[6] = {ma.z + fa.z, ma.w + fa.w, mb.x + fb.x,
                            mb.y + fb.y, mb.z + fb.z, mb.w + fb.w};
        const float mu  = S * (1.0f / 128.0f);
        const float var = fmaf(SS, 1.0f / 128.0f, -mu * mu);
        const float inv = rsqrtf(var + LN_EPS);
#pragma unroll
        for (int j = 0; j < 6; ++j) {
            const float pre = fmaf(inv, fmaf(-mu, gwv[j], d[j]), gwv[6 + j]);
            p1[j] = 1.0f / (1.0f + __expf(-pre));
        }
    }

    float* o = out + (size_t)i0 * DD;          // 48B-aligned (16B ok)
    if (two) {
        const f32x4 w0 = {p0[0], p0[1], p0[2], p0[3]};
        const f32x4 w1 = {p0[4], p0[5], p1[0], p1[1]};
        const f32x4 w2 = {p1[2], p1[3], p1[4], p1[5]};
        __builtin_nontemporal_store(w0, reinterpret_cast<f32x4*>(o));
        __builtin_nontemporal_store(w1, reinterpret_cast<f32x4*>(o + 4));
        __builtin_nontemporal_store(w2, reinterpret_cast<f32x4*>(o + 8));
    } else {
        const f32x4 w0 = {p0[0], p0[1], p0[2], p0[3]};
        const f32x2 w1 = {p0[4], p0[5]};
        __builtin_nontemporal_store(w0, reinterpret_cast<f32x4*>(o));
        __builtin_nontemporal_store(w1, reinterpret_cast<f32x2*>(o + 4));
    }
}

extern "C" void kernel_launch(void* const* d_in, const int* in_sizes, int n_in,
                              void* d_out, int out_size, void* d_ws, size_t ws_size,
                              hipStream_t stream) {
    const float* x     = (const float*)d_in[0];
    const float* e     = (const float*)d_in[1];
    const int*   row   = (const int*)d_in[2];
    const int*   col   = (const int*)d_in[3];
    const float* gamma = (const float*)d_in[4];
    const float* beta  = (const float*)d_in[5];
    const float* W     = (const float*)d_in[6];
    const float* b     = (const float*)d_in[7];
    float* out = (float*)d_out;

    const int N   = in_sizes[0] / (DD * FF);   // 100000 (element-count convention)
    const int E   = in_sizes[1] / (DD * FF);   // 20000
    const int NNZ = in_sizes[2];               // 1000000

    float* nodeT = (float*)d_ws;               // N*8 f32 = 3.2 MB
    float* edgeT = nodeT + (size_t)N * 8;      // E*8 f32 = 0.64 MB
    float* gwbw  = edgeT + (size_t)E * 8;      // 12 f32

    {
        const int totalPairs = ((N + 1) >> 1) + ((E + 1) >> 1);
        const int blocks = (totalPairs + 15) / 16;     // 3750
        entity_kernel<<<blocks, 256, 0, stream>>>(x, e, gamma, beta, W, b,
                                                  nodeT, edgeT, gwbw, N, E);
    }
    {
        const int threads = (NNZ + 1) / 2;             // 2 incidences/thread
        const int blocks = (threads + 255) / 256;      // 1954
        incidence2_kernel<<<blocks, 256, 0, stream>>>(nodeT, edgeT, row, col,
                                                      gwbw, out, NNZ);
    }
}